// Round 1
// baseline (1469.858 us; speedup 1.0000x reference)
//
#include <hip/hip_runtime.h>
#include <math.h>

#define B 8
#define N 4096
#define W 64
#define R 4
#define EPSF 1e-8f

// ---- workspace layout (float offsets) ----
#define O_Y     0                       // (B,N,8)  [A|C]  = L  * G8   (atomic accum, zeroed)
#define O_Z     (O_Y + B*N*8)           // (B,N,8)  [At|Ct]= L^T* G8   (atomic accum, zeroed)
#define O_G8    (O_Z + B*N*8)           // (B,N,8)  [g | ww*g]
#define O_WW    (O_G8 + B*N*8)          // (B,N)
#define O_USAGE (O_WW + B*N)            // (B,N)
#define O_ZW    (O_USAGE + B*N)         // (B,N)   write_strength * cos-sim
#define O_ALLOC (O_ZW + B*N)            // (B,N)
#define O_ZR    (O_ALLOC + B*N)         // (B,N,R) read_strength * cos-sim
#define O_DIAG  (O_ZR + B*N*R)          // (B,N)   L[b,i,i]
#define O_MEM2  (O_DIAG + B*N)          // (B,N,W) updated memory
#define O_SCAL  (O_MEM2 + B*N*W)        // per batch 32: S[4],T[4],maxr[4],denomr[4]

// ---------- DPP wave64 sum (VALU pipe, result in lane 63) ----------
template <int CTRL, int RM>
__device__ __forceinline__ float dpp_add(float x) {
  int t = __builtin_amdgcn_update_dpp(0, __float_as_int(x), CTRL, RM, 0xf, true);
  return x + __int_as_float(t);
}
__device__ __forceinline__ float wave_sum64(float x) {
  x = dpp_add<0x111, 0xf>(x);  // row_shr:1
  x = dpp_add<0x112, 0xf>(x);  // row_shr:2
  x = dpp_add<0x114, 0xf>(x);  // row_shr:4
  x = dpp_add<0x118, 0xf>(x);  // row_shr:8
  x = dpp_add<0x142, 0xa>(x);  // row_bcast:15
  x = dpp_add<0x143, 0xc>(x);  // row_bcast:31
  return x;                    // lane 63 holds the full 64-lane sum
}

// ---------- K1: usage' and scaled write-sim per (b,n); one wave per row ----------
__global__ void __launch_bounds__(256) k1_prep(
    const float* __restrict__ mem, const float* __restrict__ wkey,
    const float* __restrict__ wstr, const float* __restrict__ g,
    const float* __restrict__ freeg, const float* __restrict__ wwgt,
    const float* __restrict__ musage, float* __restrict__ zw,
    float* __restrict__ usage) {
  int wid  = blockIdx.x * 4 + (threadIdx.x >> 6);   // b*N + n
  int lane = threadIdx.x & 63;
  int b = wid >> 12;
  float m = mem[(size_t)wid * W + lane];
  float k = wkey[b * W + lane];
  float d = m * k, nm = m * m, nk = k * k;
#pragma unroll
  for (int o = 32; o; o >>= 1) {
    d += __shfl_xor(d, o); nm += __shfl_xor(nm, o); nk += __shfl_xor(nk, o);
  }
  if (lane == 0) {
    float sim = d / (sqrtf(nk) * sqrtf(nm) + EPSF);
    zw[wid] = wstr[b] * sim;
    float u = musage[wid], wv = wwgt[wid];
    float uw = u + wv - u * wv;
    float prod = 1.f;
#pragma unroll
    for (int r = 0; r < R; ++r) prod *= (1.f - g[(size_t)wid * R + r] * freeg[b * R + r]);
    usage[wid] = uw * prod;
  }
}

// ---------- K4: diagonal extraction ----------
__global__ void __launch_bounds__(256) k4_diag(const float* __restrict__ L,
                                               float* __restrict__ diag) {
  int tid = blockIdx.x * 256 + threadIdx.x;   // b*N + i
  int b = tid >> 12, i = tid & 4095;
  diag[tid] = L[(size_t)b * N * N + (size_t)i * N + i];
}

// ---------- K2: sort-free allocation weights via rank log-sum ----------
__global__ void __launch_bounds__(256) k2_alloc(const float* __restrict__ usage,
                                                float* __restrict__ alloc) {
  __shared__ float2 s[N];   // (u, log u) : 32 KiB
  int b = blockIdx.x >> 4;
  const float* u = usage + b * N;
  for (int i = threadIdx.x; i < N; i += 256) {
    float v = u[i];
    s[i] = make_float2(v, __logf(v));
  }
  __syncthreads();
  int n = (blockIdx.x & 15) * 256 + threadIdx.x;
  float un = u[n];
  float acc = 0.f;
#pragma unroll 4
  for (int m = 0; m < N; ++m) {
    float2 v = s[m];
    acc += (v.x < un) ? v.y : 0.f;
  }
  alloc[b * N + n] = (1.f - un) * __expf(acc);
}

// ---------- K3: cbw softmax, ww, G8, S/T scalars (one block per batch) ----------
__global__ void __launch_bounds__(1024) k3_ww(
    const float* __restrict__ g, const float* __restrict__ p,
    const float* __restrict__ agp, const float* __restrict__ wgp,
    const float* __restrict__ zw, const float* __restrict__ alloc,
    float* __restrict__ ww, float* __restrict__ g8, float* __restrict__ scal) {
  __shared__ float red[1024];
  int b = blockIdx.x, t = threadIdx.x;
  const float* z = zw + b * N;
  float mx = -1e30f;
  for (int i = t; i < N; i += 1024) mx = fmaxf(mx, z[i]);
  red[t] = mx; __syncthreads();
  for (int s = 512; s; s >>= 1) { if (t < s) red[t] = fmaxf(red[t], red[t + s]); __syncthreads(); }
  mx = red[0]; __syncthreads();
  float sm = 0.f;
  for (int i = t; i < N; i += 1024) sm += __expf(z[i] - mx);
  red[t] = sm; __syncthreads();
  for (int s = 512; s; s >>= 1) { if (t < s) red[t] += red[t + s]; __syncthreads(); }
  float denom = red[0]; __syncthreads();

  float ag = agp[b], wg = wgp[b];
  float pS[4] = {0.f, 0.f, 0.f, 0.f}, pT[4] = {0.f, 0.f, 0.f, 0.f};
  for (int i = t; i < N; i += 1024) {
    float cbw = __expf(z[i] - mx) / denom;
    float w = wg * (ag * alloc[b * N + i] + (1.f - ag) * cbw);
    ww[b * N + i] = w;
    float4 gv = *(const float4*)(g + (size_t)(b * N + i) * 4);
    float4 hi = make_float4(w * gv.x, w * gv.y, w * gv.z, w * gv.w);
    float4* gp = (float4*)(g8 + (size_t)(b * N + i) * 8);
    gp[0] = gv; gp[1] = hi;
    float pv = p[b * N + i];
    pS[0] += pv * gv.x; pS[1] += pv * gv.y; pS[2] += pv * gv.z; pS[3] += pv * gv.w;
    pT[0] += hi.x;      pT[1] += hi.y;      pT[2] += hi.z;      pT[3] += hi.w;
  }
  float arr8[8] = {pS[0], pS[1], pS[2], pS[3], pT[0], pT[1], pT[2], pT[3]};
#pragma unroll
  for (int r = 0; r < 8; ++r) {
    red[t] = arr8[r]; __syncthreads();
    for (int s = 512; s; s >>= 1) { if (t < s) red[t] += red[t + s]; __syncthreads(); }
    if (t == 0) scal[b * 32 + r] = red[0];
    __syncthreads();
  }
}

// ---------- K6: memory update + scaled read sims; one wave per row ----------
__global__ void __launch_bounds__(256) k6_mem(
    const float* __restrict__ mem, const float* __restrict__ erase,
    const float* __restrict__ wvec, const float* __restrict__ rkeys,
    const float* __restrict__ rstr, const float* __restrict__ ww,
    float* __restrict__ mem2, float* __restrict__ zr) {
  int wid  = blockIdx.x * 4 + (threadIdx.x >> 6);   // b*N + n
  int lane = threadIdx.x & 63;
  int b = wid >> 12;
  float w = ww[wid];
  float m = mem[(size_t)wid * W + lane];
  float e = erase[b * W + lane], v = wvec[b * W + lane];
  float m2 = m * (1.f - w * e) + w * v;
  mem2[(size_t)wid * W + lane] = m2;
  float k0 = rkeys[(b * W + lane) * R + 0];
  float k1 = rkeys[(b * W + lane) * R + 1];
  float k2 = rkeys[(b * W + lane) * R + 2];
  float k3 = rkeys[(b * W + lane) * R + 3];
  float nm = m2 * m2;
  float d0 = m2 * k0, d1 = m2 * k1, d2 = m2 * k2, d3 = m2 * k3;
  float e0 = k0 * k0, e1 = k1 * k1, e2 = k2 * k2, e3 = k3 * k3;
#pragma unroll
  for (int o = 32; o; o >>= 1) {
    nm += __shfl_xor(nm, o);
    d0 += __shfl_xor(d0, o); d1 += __shfl_xor(d1, o);
    d2 += __shfl_xor(d2, o); d3 += __shfl_xor(d3, o);
    e0 += __shfl_xor(e0, o); e1 += __shfl_xor(e1, o);
    e2 += __shfl_xor(e2, o); e3 += __shfl_xor(e3, o);
  }
  if (lane == 0) {
    float snm = sqrtf(nm);
    zr[(size_t)wid * R + 0] = rstr[b * R + 0] * d0 / (snm * sqrtf(e0) + EPSF);
    zr[(size_t)wid * R + 1] = rstr[b * R + 1] * d1 / (snm * sqrtf(e1) + EPSF);
    zr[(size_t)wid * R + 2] = rstr[b * R + 2] * d2 / (snm * sqrtf(e2) + EPSF);
    zr[(size_t)wid * R + 3] = rstr[b * R + 3] * d3 / (snm * sqrtf(e3) + EPSF);
  }
}

// ---------- K5: THE BIG ONE — one pass over L computing Y=L*G8 and Z=L^T*G8 ----------
// grid: 1024 blocks = B(8) x bandblk(4) x slice(32); block 256 = 4 waves.
// wave owns 256 contiguous columns (4/lane, dwordx4) and sweeps 128 rows.
__global__ void __launch_bounds__(256, 4) k5_link(
    const float* __restrict__ L, const float* __restrict__ g8,
    float* __restrict__ Y, float* __restrict__ Z) {
  int bi = blockIdx.x;
  int b = bi >> 7;
  int band = (bi >> 5) & 3;
  int slice = bi & 31;
  int wv = threadIdx.x >> 6;
  int lane = threadIdx.x & 63;
  int j0 = band * 1024 + wv * 256 + lane * 4;
  const float* g8b = g8 + (size_t)b * N * 8;
  float g8c[4][8];
#pragma unroll
  for (int c = 0; c < 4; ++c) {
    float4 a = *(const float4*)(g8b + (size_t)(j0 + c) * 8);
    float4 d = *(const float4*)(g8b + (size_t)(j0 + c) * 8 + 4);
    g8c[c][0] = a.x; g8c[c][1] = a.y; g8c[c][2] = a.z; g8c[c][3] = a.w;
    g8c[c][4] = d.x; g8c[c][5] = d.y; g8c[c][6] = d.z; g8c[c][7] = d.w;
  }
  float zacc[4][8];
#pragma unroll
  for (int c = 0; c < 4; ++c)
#pragma unroll
    for (int r = 0; r < 8; ++r) zacc[c][r] = 0.f;

  const float* Lb = L + (size_t)b * N * N;
  float* Yb = Y + (size_t)b * N * 8;
  int i0 = slice * 128;
  for (int ii = 0; ii < 128; ++ii) {
    int ig = i0 + ii;
    float4 lv = *(const float4*)(Lb + (size_t)ig * N + j0);
    float4 ra = *(const float4*)(g8b + (size_t)ig * 8);       // uniform -> s_load
    float4 rb = *(const float4*)(g8b + (size_t)ig * 8 + 4);
    float rr[8] = {ra.x, ra.y, ra.z, ra.w, rb.x, rb.y, rb.z, rb.w};
    float rs[8];
#pragma unroll
    for (int r = 0; r < 8; ++r) {
      rs[r] = fmaf(lv.x, g8c[0][r],
              fmaf(lv.y, g8c[1][r],
              fmaf(lv.z, g8c[2][r], lv.w * g8c[3][r])));
      zacc[0][r] = fmaf(lv.x, rr[r], zacc[0][r]);
      zacc[1][r] = fmaf(lv.y, rr[r], zacc[1][r]);
      zacc[2][r] = fmaf(lv.z, rr[r], zacc[2][r]);
      zacc[3][r] = fmaf(lv.w, rr[r], zacc[3][r]);
    }
#pragma unroll
    for (int r = 0; r < 8; ++r) rs[r] = wave_sum64(rs[r]);
    if (lane == 63) {
#pragma unroll
      for (int r = 0; r < 8; ++r) unsafeAtomicAdd(&Yb[(size_t)ig * 8 + r], rs[r]);
    }
  }
  float* Zb = Z + (size_t)b * N * 8;
#pragma unroll
  for (int c = 0; c < 4; ++c)
#pragma unroll
    for (int r = 0; r < 8; ++r)
      unsafeAtomicAdd(&Zb[(size_t)(j0 + c) * 8 + r], zacc[c][r]);
}

// ---------- K7: cbr softmax stats per (b,r) ----------
__global__ void __launch_bounds__(256) k7_stats(const float* __restrict__ zr,
                                                float* __restrict__ scal) {
  __shared__ float red[256];
  int b = blockIdx.x >> 2, r = blockIdx.x & 3, t = threadIdx.x;
  float mx = -1e30f;
  for (int n = t; n < N; n += 256) mx = fmaxf(mx, zr[((size_t)(b * N + n)) * 4 + r]);
  red[t] = mx; __syncthreads();
  for (int s = 128; s; s >>= 1) { if (t < s) red[t] = fmaxf(red[t], red[t + s]); __syncthreads(); }
  mx = red[0]; __syncthreads();
  float sm = 0.f;
  for (int n = t; n < N; n += 256) sm += __expf(zr[((size_t)(b * N + n)) * 4 + r] - mx);
  red[t] = sm; __syncthreads();
  for (int s = 128; s; s >>= 1) { if (t < s) red[t] += red[t + s]; __syncthreads(); }
  if (t == 0) { scal[b * 32 + 8 + r] = mx; scal[b * 32 + 12 + r] = red[0]; }
}

// ---------- K8: fwd/bwd/cbr -> rw -> read_vectors ----------
__global__ void __launch_bounds__(256) k8_final(
    const float* __restrict__ mem2, const float* __restrict__ Y,
    const float* __restrict__ Z, const float* __restrict__ zr,
    const float* __restrict__ g, const float* __restrict__ ww,
    const float* __restrict__ diag, const float* __restrict__ p,
    const float* __restrict__ modes, const float* __restrict__ scal,
    float* __restrict__ out) {
  int b = blockIdx.x >> 4;
  int wv = threadIdx.x >> 6;
  int lane = threadIdx.x & 63;
  int n0 = (blockIdx.x & 15) * 256 + wv * 64;
  const float* sc = scal + b * 32;
  float S[4], T[4], mxr[4], dnr[4], md0[4], md1[4], md2[4];
#pragma unroll
  for (int r = 0; r < 4; ++r) {
    S[r] = sc[r]; T[r] = sc[4 + r]; mxr[r] = sc[8 + r]; dnr[r] = sc[12 + r];
    md0[r] = modes[b * 12 + r];
    md1[r] = modes[b * 12 + 4 + r];
    md2[r] = modes[b * 12 + 8 + r];
  }
  float acc[4] = {0.f, 0.f, 0.f, 0.f};
  for (int k = 0; k < 64; ++k) {
    int bn = b * N + n0 + k;
    float w = ww[bn], pv = p[bn], dgv = diag[bn];
    float D = (1.f - 2.f * w) * dgv + w * pv;
    const float* y  = Y  + (size_t)bn * 8;
    const float* z  = Z  + (size_t)bn * 8;
    const float* z4 = zr + (size_t)bn * 4;
    const float* g4 = g  + (size_t)bn * 4;
    float rw[4];
#pragma unroll
    for (int r = 0; r < 4; ++r) {
      float fwd = (1.f - w) * y[r] - y[4 + r] + w * S[r] - D * g4[r];
      float bwd = (1.f - w) * z[r] - z[4 + r] + pv * T[r] - D * g4[r];
      float cbr = __expf(z4[r] - mxr[r]) / dnr[r];
      rw[r] = md0[r] * bwd + md1[r] * cbr + md2[r] * fwd;
    }
    float mv = mem2[(size_t)bn * 64 + lane];
#pragma unroll
    for (int r = 0; r < 4; ++r) acc[r] += mv * rw[r];
  }
#pragma unroll
  for (int r = 0; r < 4; ++r)
    unsafeAtomicAdd(&out[b * 256 + lane * 4 + r], acc[r]);
}

extern "C" void kernel_launch(void* const* d_in, const int* in_sizes, int n_in,
                              void* d_out, int out_size, void* d_ws, size_t ws_size,
                              hipStream_t stream) {
  (void)in_sizes; (void)n_in; (void)out_size; (void)ws_size;
  const float* erase  = (const float*)d_in[0];
  const float* freeg  = (const float*)d_in[1];
  const float* ag     = (const float*)d_in[2];
  const float* wg     = (const float*)d_in[3];
  const float* modes  = (const float*)d_in[4];
  const float* rstr   = (const float*)d_in[5];
  const float* rkeys  = (const float*)d_in[6];
  const float* wvec   = (const float*)d_in[7];
  const float* wkey   = (const float*)d_in[8];
  const float* wstr   = (const float*)d_in[9];
  const float* mem    = (const float*)d_in[10];
  const float* g      = (const float*)d_in[11];
  const float* wwgt   = (const float*)d_in[12];
  const float* musage = (const float*)d_in[13];
  const float* L      = (const float*)d_in[14];
  const float* p      = (const float*)d_in[15];
  float* ws  = (float*)d_ws;
  float* out = (float*)d_out;

  // zero the atomic accumulators (Y,Z contiguous) and the output
  hipMemsetAsync(ws + O_Y, 0, (size_t)(B * N * 16) * sizeof(float), stream);
  hipMemsetAsync(out, 0, (size_t)(B * W * R) * sizeof(float), stream);

  k1_prep<<<8192, 256, 0, stream>>>(mem, wkey, wstr, g, freeg, wwgt, musage,
                                    ws + O_ZW, ws + O_USAGE);
  k4_diag<<<128, 256, 0, stream>>>(L, ws + O_DIAG);
  k2_alloc<<<128, 256, 0, stream>>>(ws + O_USAGE, ws + O_ALLOC);
  k3_ww<<<B, 1024, 0, stream>>>(g, p, ag, wg, ws + O_ZW, ws + O_ALLOC,
                                ws + O_WW, ws + O_G8, ws + O_SCAL);
  k6_mem<<<8192, 256, 0, stream>>>(mem, erase, wvec, rkeys, rstr, ws + O_WW,
                                   ws + O_MEM2, ws + O_ZR);
  k5_link<<<1024, 256, 0, stream>>>(L, ws + O_G8, ws + O_Y, ws + O_Z);
  k7_stats<<<32, 256, 0, stream>>>(ws + O_ZR, ws + O_SCAL);
  k8_final<<<128, 256, 0, stream>>>(ws + O_MEM2, ws + O_Y, ws + O_Z, ws + O_ZR,
                                    g, ws + O_WW, ws + O_DIAG, p, modes,
                                    ws + O_SCAL, out);
}

// Round 2
// 946.992 us; speedup vs baseline: 1.5521x; 1.5521x over previous
//
#include <hip/hip_runtime.h>
#include <math.h>

#define B 8
#define N 4096
#define W 64
#define R 4
#define EPSF 1e-8f

// ---- workspace layout (float offsets) ----
#define O_Y     0                       // (B,N,8)  [A|C]  = L  * G8   (reduced)
#define O_Z     (O_Y + B*N*8)           // (B,N,8)  [At|Ct]= L^T* G8   (reduced)
#define O_G8    (O_Z + B*N*8)           // (B,N,8)  [g | ww*g]
#define O_WW    (O_G8 + B*N*8)          // (B,N)
#define O_USAGE (O_WW + B*N)            // (B,N)
#define O_ZW    (O_USAGE + B*N)         // (B,N)   write_strength * cos-sim
#define O_ALLOC (O_ZW + B*N)            // (B,N)
#define O_ZR    (O_ALLOC + B*N)         // (B,N,R) read_strength * cos-sim
#define O_DIAG  (O_ZR + B*N*R)          // (B,N)   L[b,i,i]
#define O_MEM2  (O_DIAG + B*N)          // (B,N,W) updated memory
#define O_SCAL  (O_MEM2 + B*N*W)        // per batch 32: S[4],T[4],maxr[4],denomr[4]
#define O_YP    (O_SCAL + 256)          // (B,16,N,8) Y partials per column-chunk
#define O_ZP    (O_YP + B*16*N*8)       // (B,32,N,8) Z partials per row-slice

// ---------- DPP wave64 sum (VALU pipe, result in lane 63) ----------
template <int CTRL, int RM>
__device__ __forceinline__ float dpp_add(float x) {
  int t = __builtin_amdgcn_update_dpp(0, __float_as_int(x), CTRL, RM, 0xf, true);
  return x + __int_as_float(t);
}
__device__ __forceinline__ float wave_sum64(float x) {
  x = dpp_add<0x111, 0xf>(x);  // row_shr:1
  x = dpp_add<0x112, 0xf>(x);  // row_shr:2
  x = dpp_add<0x114, 0xf>(x);  // row_shr:4
  x = dpp_add<0x118, 0xf>(x);  // row_shr:8
  x = dpp_add<0x142, 0xa>(x);  // row_bcast:15
  x = dpp_add<0x143, 0xc>(x);  // row_bcast:31
  return x;                    // lane 63 holds the full 64-lane sum
}

// ---------- K1: usage', write-sim, and diag(L) per (b,n); one wave per row ----------
__global__ void __launch_bounds__(256) k1_prep(
    const float* __restrict__ mem, const float* __restrict__ wkey,
    const float* __restrict__ wstr, const float* __restrict__ g,
    const float* __restrict__ freeg, const float* __restrict__ wwgt,
    const float* __restrict__ musage, const float* __restrict__ L,
    float* __restrict__ zw, float* __restrict__ usage,
    float* __restrict__ diag) {
  int wid  = blockIdx.x * 4 + (threadIdx.x >> 6);   // b*N + n
  int lane = threadIdx.x & 63;
  int b = wid >> 12;
  float m = mem[(size_t)wid * W + lane];
  float k = wkey[b * W + lane];
  float d = m * k, nm = m * m, nk = k * k;
#pragma unroll
  for (int o = 32; o; o >>= 1) {
    d += __shfl_xor(d, o); nm += __shfl_xor(nm, o); nk += __shfl_xor(nk, o);
  }
  if (lane == 0) {
    float sim = d / (sqrtf(nk) * sqrtf(nm) + EPSF);
    zw[wid] = wstr[b] * sim;
    float u = musage[wid], wv = wwgt[wid];
    float uw = u + wv - u * wv;
    float prod = 1.f;
#pragma unroll
    for (int r = 0; r < R; ++r) prod *= (1.f - g[(size_t)wid * R + r] * freeg[b * R + r]);
    usage[wid] = uw * prod;
    diag[wid] = L[(size_t)wid * N + (wid & 4095)];   // L[b][n][n]
  }
}

// ---------- K2: sort-free allocation weights via rank log-sum ----------
__global__ void __launch_bounds__(256) k2_alloc(const float* __restrict__ usage,
                                                float* __restrict__ alloc) {
  __shared__ float2 s[N];   // (u, log u) : 32 KiB
  int b = blockIdx.x >> 4;
  const float* u = usage + b * N;
  for (int i = threadIdx.x; i < N; i += 256) {
    float v = u[i];
    s[i] = make_float2(v, __logf(v));
  }
  __syncthreads();
  int n = (blockIdx.x & 15) * 256 + threadIdx.x;
  float un = u[n];
  float acc = 0.f;
#pragma unroll 4
  for (int m = 0; m < N; ++m) {
    float2 v = s[m];
    acc += (v.x < un) ? v.y : 0.f;
  }
  alloc[b * N + n] = (1.f - un) * __expf(acc);
}

// ---------- K3: cbw softmax, ww, G8, S/T scalars (one block per batch) ----------
__global__ void __launch_bounds__(1024) k3_ww(
    const float* __restrict__ g, const float* __restrict__ p,
    const float* __restrict__ agp, const float* __restrict__ wgp,
    const float* __restrict__ zw, const float* __restrict__ alloc,
    float* __restrict__ ww, float* __restrict__ g8, float* __restrict__ scal) {
  __shared__ float red[1024];
  int b = blockIdx.x, t = threadIdx.x;
  const float* z = zw + b * N;
  float mx = -1e30f;
  for (int i = t; i < N; i += 1024) mx = fmaxf(mx, z[i]);
  red[t] = mx; __syncthreads();
  for (int s = 512; s; s >>= 1) { if (t < s) red[t] = fmaxf(red[t], red[t + s]); __syncthreads(); }
  mx = red[0]; __syncthreads();
  float sm = 0.f;
  for (int i = t; i < N; i += 1024) sm += __expf(z[i] - mx);
  red[t] = sm; __syncthreads();
  for (int s = 512; s; s >>= 1) { if (t < s) red[t] += red[t + s]; __syncthreads(); }
  float denom = red[0]; __syncthreads();

  float ag = agp[b], wg = wgp[b];
  float pS[4] = {0.f, 0.f, 0.f, 0.f}, pT[4] = {0.f, 0.f, 0.f, 0.f};
  for (int i = t; i < N; i += 1024) {
    float cbw = __expf(z[i] - mx) / denom;
    float w = wg * (ag * alloc[b * N + i] + (1.f - ag) * cbw);
    ww[b * N + i] = w;
    float4 gv = *(const float4*)(g + (size_t)(b * N + i) * 4);
    float4 hi = make_float4(w * gv.x, w * gv.y, w * gv.z, w * gv.w);
    float4* gp = (float4*)(g8 + (size_t)(b * N + i) * 8);
    gp[0] = gv; gp[1] = hi;
    float pv = p[b * N + i];
    pS[0] += pv * gv.x; pS[1] += pv * gv.y; pS[2] += pv * gv.z; pS[3] += pv * gv.w;
    pT[0] += hi.x;      pT[1] += hi.y;      pT[2] += hi.z;      pT[3] += hi.w;
  }
  float arr8[8] = {pS[0], pS[1], pS[2], pS[3], pT[0], pT[1], pT[2], pT[3]};
#pragma unroll
  for (int r = 0; r < 8; ++r) {
    red[t] = arr8[r]; __syncthreads();
    for (int s = 512; s; s >>= 1) { if (t < s) red[t] += red[t + s]; __syncthreads(); }
    if (t == 0) scal[b * 32 + r] = red[0];
    __syncthreads();
  }
}

// ---------- K6: memory update + scaled read sims; one wave per row ----------
__global__ void __launch_bounds__(256) k6_mem(
    const float* __restrict__ mem, const float* __restrict__ erase,
    const float* __restrict__ wvec, const float* __restrict__ rkeys,
    const float* __restrict__ rstr, const float* __restrict__ ww,
    float* __restrict__ mem2, float* __restrict__ zr) {
  int wid  = blockIdx.x * 4 + (threadIdx.x >> 6);   // b*N + n
  int lane = threadIdx.x & 63;
  int b = wid >> 12;
  float w = ww[wid];
  float m = mem[(size_t)wid * W + lane];
  float e = erase[b * W + lane], v = wvec[b * W + lane];
  float m2 = m * (1.f - w * e) + w * v;
  mem2[(size_t)wid * W + lane] = m2;
  float k0 = rkeys[(b * W + lane) * R + 0];
  float k1 = rkeys[(b * W + lane) * R + 1];
  float k2 = rkeys[(b * W + lane) * R + 2];
  float k3 = rkeys[(b * W + lane) * R + 3];
  float nm = m2 * m2;
  float d0 = m2 * k0, d1 = m2 * k1, d2 = m2 * k2, d3 = m2 * k3;
  float e0 = k0 * k0, e1 = k1 * k1, e2 = k2 * k2, e3 = k3 * k3;
#pragma unroll
  for (int o = 32; o; o >>= 1) {
    nm += __shfl_xor(nm, o);
    d0 += __shfl_xor(d0, o); d1 += __shfl_xor(d1, o);
    d2 += __shfl_xor(d2, o); d3 += __shfl_xor(d3, o);
    e0 += __shfl_xor(e0, o); e1 += __shfl_xor(e1, o);
    e2 += __shfl_xor(e2, o); e3 += __shfl_xor(e3, o);
  }
  if (lane == 0) {
    float snm = sqrtf(nm);
    zr[(size_t)wid * R + 0] = rstr[b * R + 0] * d0 / (snm * sqrtf(e0) + EPSF);
    zr[(size_t)wid * R + 1] = rstr[b * R + 1] * d1 / (snm * sqrtf(e1) + EPSF);
    zr[(size_t)wid * R + 2] = rstr[b * R + 2] * d2 / (snm * sqrtf(e2) + EPSF);
    zr[(size_t)wid * R + 3] = rstr[b * R + 3] * d3 / (snm * sqrtf(e3) + EPSF);
  }
}

// ---------- K5: one pass over L computing Y=L*G8 and Z=L^T*G8, ATOMIC-FREE ----------
// grid: 1024 blocks = B(8) x band(4) x slice(32); block 256 = 4 waves.
// wave owns 256 contiguous columns (4/lane, dwordx4) and sweeps 128 rows.
// Y per-row wave sums -> Ypart[b][band*4+wv][i][8]   (16 exclusive partials)
// Z per-lane col accum -> Zpart[b][slice][j][8]      (32 exclusive partials)
__global__ void __launch_bounds__(256, 4) k5_link(
    const float* __restrict__ L, const float* __restrict__ g8,
    float* __restrict__ Yp, float* __restrict__ Zp) {
  int bi = blockIdx.x;
  int b = bi >> 7;
  int band = (bi >> 5) & 3;
  int slice = bi & 31;
  int wv = threadIdx.x >> 6;
  int lane = threadIdx.x & 63;
  int j0 = band * 1024 + wv * 256 + lane * 4;
  const float* g8b = g8 + (size_t)b * N * 8;
  float g8c[4][8];
#pragma unroll
  for (int c = 0; c < 4; ++c) {
    float4 a = *(const float4*)(g8b + (size_t)(j0 + c) * 8);
    float4 d = *(const float4*)(g8b + (size_t)(j0 + c) * 8 + 4);
    g8c[c][0] = a.x; g8c[c][1] = a.y; g8c[c][2] = a.z; g8c[c][3] = a.w;
    g8c[c][4] = d.x; g8c[c][5] = d.y; g8c[c][6] = d.z; g8c[c][7] = d.w;
  }
  float zacc[4][8];
#pragma unroll
  for (int c = 0; c < 4; ++c)
#pragma unroll
    for (int r = 0; r < 8; ++r) zacc[c][r] = 0.f;

  const float* Lb = L + (size_t)b * N * N;
  int chunk = band * 4 + wv;                       // 0..15
  float* Ypb = Yp + ((size_t)(b * 16 + chunk)) * N * 8;
  int i0 = slice * 128;
  for (int ii = 0; ii < 128; ++ii) {
    int ig = i0 + ii;
    float4 lv = *(const float4*)(Lb + (size_t)ig * N + j0);
    float4 ra = *(const float4*)(g8b + (size_t)ig * 8);       // wave-uniform -> s_load
    float4 rb = *(const float4*)(g8b + (size_t)ig * 8 + 4);
    float rr[8] = {ra.x, ra.y, ra.z, ra.w, rb.x, rb.y, rb.z, rb.w};
    float rs[8];
#pragma unroll
    for (int r = 0; r < 8; ++r) {
      rs[r] = fmaf(lv.x, g8c[0][r],
              fmaf(lv.y, g8c[1][r],
              fmaf(lv.z, g8c[2][r], lv.w * g8c[3][r])));
      zacc[0][r] = fmaf(lv.x, rr[r], zacc[0][r]);
      zacc[1][r] = fmaf(lv.y, rr[r], zacc[1][r]);
      zacc[2][r] = fmaf(lv.z, rr[r], zacc[2][r]);
      zacc[3][r] = fmaf(lv.w, rr[r], zacc[3][r]);
    }
#pragma unroll
    for (int r = 0; r < 8; ++r) rs[r] = wave_sum64(rs[r]);
    if (lane == 63) {
      float4* yo = (float4*)(Ypb + (size_t)ig * 8);
      yo[0] = make_float4(rs[0], rs[1], rs[2], rs[3]);
      yo[1] = make_float4(rs[4], rs[5], rs[6], rs[7]);
    }
  }
  float* Zpb = Zp + ((size_t)(b * 32 + slice)) * N * 8;
#pragma unroll
  for (int c = 0; c < 4; ++c) {
    float4* zo = (float4*)(Zpb + (size_t)(j0 + c) * 8);
    zo[0] = make_float4(zacc[c][0], zacc[c][1], zacc[c][2], zacc[c][3]);
    zo[1] = make_float4(zacc[c][4], zacc[c][5], zacc[c][6], zacc[c][7]);
  }
}

// ---------- KR: fold partials: Y = sum_16 Ypart, Z = sum_32 Zpart ----------
__global__ void __launch_bounds__(256) kR_reduce(
    const float* __restrict__ Yp, const float* __restrict__ Zp,
    float* __restrict__ Y, float* __restrict__ Z) {
  int t = blockIdx.x * 256 + threadIdx.x;   // float4-element index, 0..131071
  if (t < 65536) {                          // Y: B * N*2 float4s
    int b = t >> 13, e = t & 8191;
    const float4* base = (const float4*)Yp + (size_t)b * 16 * 8192 + e;
    float4 acc = make_float4(0.f, 0.f, 0.f, 0.f);
#pragma unroll 4
    for (int c = 0; c < 16; ++c) {
      float4 v = base[(size_t)c * 8192];
      acc.x += v.x; acc.y += v.y; acc.z += v.z; acc.w += v.w;
    }
    ((float4*)Y)[t] = acc;
  } else {
    int u = t - 65536;
    int b = u >> 13, e = u & 8191;
    const float4* base = (const float4*)Zp + (size_t)b * 32 * 8192 + e;
    float4 acc = make_float4(0.f, 0.f, 0.f, 0.f);
#pragma unroll 4
    for (int s = 0; s < 32; ++s) {
      float4 v = base[(size_t)s * 8192];
      acc.x += v.x; acc.y += v.y; acc.z += v.z; acc.w += v.w;
    }
    ((float4*)Z)[u] = acc;
  }
}

// ---------- K7: cbr softmax stats per (b,r) ----------
__global__ void __launch_bounds__(256) k7_stats(const float* __restrict__ zr,
                                                float* __restrict__ scal) {
  __shared__ float red[256];
  int b = blockIdx.x >> 2, r = blockIdx.x & 3, t = threadIdx.x;
  float mx = -1e30f;
  for (int n = t; n < N; n += 256) mx = fmaxf(mx, zr[((size_t)(b * N + n)) * 4 + r]);
  red[t] = mx; __syncthreads();
  for (int s = 128; s; s >>= 1) { if (t < s) red[t] = fmaxf(red[t], red[t + s]); __syncthreads(); }
  mx = red[0]; __syncthreads();
  float sm = 0.f;
  for (int n = t; n < N; n += 256) sm += __expf(zr[((size_t)(b * N + n)) * 4 + r] - mx);
  red[t] = sm; __syncthreads();
  for (int s = 128; s; s >>= 1) { if (t < s) red[t] += red[t + s]; __syncthreads(); }
  if (t == 0) { scal[b * 32 + 8 + r] = mx; scal[b * 32 + 12 + r] = red[0]; }
}

// ---------- K8: fwd/bwd/cbr -> rw -> read_vectors ----------
__global__ void __launch_bounds__(256) k8_final(
    const float* __restrict__ mem2, const float* __restrict__ Y,
    const float* __restrict__ Z, const float* __restrict__ zr,
    const float* __restrict__ g, const float* __restrict__ ww,
    const float* __restrict__ diag, const float* __restrict__ p,
    const float* __restrict__ modes, const float* __restrict__ scal,
    float* __restrict__ out) {
  int b = blockIdx.x >> 4;
  int wv = threadIdx.x >> 6;
  int lane = threadIdx.x & 63;
  int n0 = (blockIdx.x & 15) * 256 + wv * 64;
  const float* sc = scal + b * 32;
  float S[4], T[4], mxr[4], dnr[4], md0[4], md1[4], md2[4];
#pragma unroll
  for (int r = 0; r < 4; ++r) {
    S[r] = sc[r]; T[r] = sc[4 + r]; mxr[r] = sc[8 + r]; dnr[r] = sc[12 + r];
    md0[r] = modes[b * 12 + r];
    md1[r] = modes[b * 12 + 4 + r];
    md2[r] = modes[b * 12 + 8 + r];
  }
  float acc[4] = {0.f, 0.f, 0.f, 0.f};
  for (int k = 0; k < 64; ++k) {
    int bn = b * N + n0 + k;
    float w = ww[bn], pv = p[bn], dgv = diag[bn];
    float D = (1.f - 2.f * w) * dgv + w * pv;
    const float* y  = Y  + (size_t)bn * 8;
    const float* z  = Z  + (size_t)bn * 8;
    const float* z4 = zr + (size_t)bn * 4;
    const float* g4 = g  + (size_t)bn * 4;
    float rw[4];
#pragma unroll
    for (int r = 0; r < 4; ++r) {
      float fwd = (1.f - w) * y[r] - y[4 + r] + w * S[r] - D * g4[r];
      float bwd = (1.f - w) * z[r] - z[4 + r] + pv * T[r] - D * g4[r];
      float cbr = __expf(z4[r] - mxr[r]) / dnr[r];
      rw[r] = md0[r] * bwd + md1[r] * cbr + md2[r] * fwd;
    }
    float mv = mem2[(size_t)bn * 64 + lane];
#pragma unroll
    for (int r = 0; r < 4; ++r) acc[r] += mv * rw[r];
  }
#pragma unroll
  for (int r = 0; r < 4; ++r)
    unsafeAtomicAdd(&out[b * 256 + lane * 4 + r], acc[r]);
}

extern "C" void kernel_launch(void* const* d_in, const int* in_sizes, int n_in,
                              void* d_out, int out_size, void* d_ws, size_t ws_size,
                              hipStream_t stream) {
  (void)in_sizes; (void)n_in; (void)out_size; (void)ws_size;
  const float* erase  = (const float*)d_in[0];
  const float* freeg  = (const float*)d_in[1];
  const float* ag     = (const float*)d_in[2];
  const float* wg     = (const float*)d_in[3];
  const float* modes  = (const float*)d_in[4];
  const float* rstr   = (const float*)d_in[5];
  const float* rkeys  = (const float*)d_in[6];
  const float* wvec   = (const float*)d_in[7];
  const float* wkey   = (const float*)d_in[8];
  const float* wstr   = (const float*)d_in[9];
  const float* mem    = (const float*)d_in[10];
  const float* g      = (const float*)d_in[11];
  const float* wwgt   = (const float*)d_in[12];
  const float* musage = (const float*)d_in[13];
  const float* L      = (const float*)d_in[14];
  const float* p      = (const float*)d_in[15];
  float* ws  = (float*)d_ws;
  float* out = (float*)d_out;

  // only the tiny output accumulator needs zeroing now (k8 atomics)
  hipMemsetAsync(out, 0, (size_t)(B * W * R) * sizeof(float), stream);

  k1_prep<<<8192, 256, 0, stream>>>(mem, wkey, wstr, g, freeg, wwgt, musage, L,
                                    ws + O_ZW, ws + O_USAGE, ws + O_DIAG);
  k2_alloc<<<128, 256, 0, stream>>>(ws + O_USAGE, ws + O_ALLOC);
  k3_ww<<<B, 1024, 0, stream>>>(g, p, ag, wg, ws + O_ZW, ws + O_ALLOC,
                                ws + O_WW, ws + O_G8, ws + O_SCAL);
  k6_mem<<<8192, 256, 0, stream>>>(mem, erase, wvec, rkeys, rstr, ws + O_WW,
                                   ws + O_MEM2, ws + O_ZR);
  k5_link<<<1024, 256, 0, stream>>>(L, ws + O_G8, ws + O_YP, ws + O_ZP);
  kR_reduce<<<512, 256, 0, stream>>>(ws + O_YP, ws + O_ZP, ws + O_Y, ws + O_Z);
  k7_stats<<<32, 256, 0, stream>>>(ws + O_ZR, ws + O_SCAL);
  k8_final<<<128, 256, 0, stream>>>(ws + O_MEM2, ws + O_Y, ws + O_Z, ws + O_ZR,
                                    g, ws + O_WW, ws + O_DIAG, p, modes,
                                    ws + O_SCAL, out);
}